// Round 6
// baseline (1941.845 us; speedup 1.0000x reference)
//
#include <hip/hip_runtime.h>
#include <cstdint>

// GF(2) encoder: out[b][n] = parity( x_row[b] & g_row[n] ), bit-packed.
// B=131072, K=512, N=1024.
//
// Packing scheme (component-major, identical for x and G so parity is
// invariant): a 256-float chunk handled by one wave becomes 4 u64 words,
// word j bit i = (chunk[i*4 + j] != 0). Row of K=512 floats = 2 chunks =
// 8 u64 = 16 u32, contiguous.
//
// R4/R5 lesson: encode has three streams {broadcast ds_read ~82us,
// VALU ~60us, stores ~82us}; SMEM replacement serialized (R5 regression).
// R6: 4 cols/thread (g[4][16]=64 VGPR, ~100 live, NO launch_bounds cap --
// R2's spill was the (256,3) cap, not the layout). LDS stream halves to
// ~41us, stores become float4.

// ---------------------------------------------------------------------------
// Pack: one wave per 256-float chunk, grid-strided. 16B/lane coalesced reads.
__global__ void pack256_kernel(const float* __restrict__ in,
                               unsigned long long* __restrict__ out,
                               int nChunks) {
    const int nWaves = (gridDim.x * blockDim.x) >> 6;
    const int lane = threadIdx.x & 63;
    for (int chunk = (blockIdx.x * blockDim.x + threadIdx.x) >> 6;
         chunk < nChunks; chunk += nWaves) {
        const float4 v =
            reinterpret_cast<const float4*>(in + (size_t)chunk * 256)[lane];
        unsigned long long m0 = __ballot(v.x != 0.0f);
        unsigned long long m1 = __ballot(v.y != 0.0f);
        unsigned long long m2 = __ballot(v.z != 0.0f);
        unsigned long long m3 = __ballot(v.w != 0.0f);
        if (lane == 0) {
            unsigned long long* o = out + (size_t)chunk * 4;
            o[0] = m0; o[1] = m1; o[2] = m2; o[3] = m3;
        }
    }
}

// ---------------------------------------------------------------------------
// Encode: block of 256 threads, each thread owns 4 columns (block = all
// 1024). 64 rows staged in LDS (4 KiB, one uint4 per thread), read back as
// broadcast ds_read_b128 (conflict-free). No occupancy cap.
__global__ void gf2_encode_kernel(
    const uint32_t* __restrict__ xp,  // [B][16] packed x rows
    const uint32_t* __restrict__ gp,  // [N][16] packed G rows
    float* __restrict__ out) {        // [B][1024]
    __shared__ uint32_t xl[64 * 16];  // 64 rows x 16 u32 = 4 KiB

    const int tid = threadIdx.x;
    const long long b0 = (long long)blockIdx.x * 64;

    // This thread's 4 G rows (64 VGPRs). G packed = 64 KiB -> L2-resident.
    uint32_t g[4][16];
#pragma unroll
    for (int j = 0; j < 4; ++j) {
        const uint4* gr =
            reinterpret_cast<const uint4*>(gp + (size_t)(tid * 4 + j) * 16);
        uint4 a = gr[0], b = gr[1], c = gr[2], d = gr[3];
        g[j][0] = a.x;  g[j][1] = a.y;  g[j][2] = a.z;  g[j][3] = a.w;
        g[j][4] = b.x;  g[j][5] = b.y;  g[j][6] = b.z;  g[j][7] = b.w;
        g[j][8] = c.x;  g[j][9] = c.y;  g[j][10] = c.z; g[j][11] = c.w;
        g[j][12] = d.x; g[j][13] = d.y; g[j][14] = d.z; g[j][15] = d.w;
    }

    // Stage 64 packed rows: 256 threads x 16B = 4 KiB, one coalesced shot.
    reinterpret_cast<uint4*>(xl)[tid] =
        reinterpret_cast<const uint4*>(xp + b0 * 16)[tid];
    __syncthreads();

    // 64 rows; x row via broadcast ds_read_b128 (conflict-free).
#pragma unroll 2
    for (int r = 0; r < 64; ++r) {
        const uint4* xr = reinterpret_cast<const uint4*>(xl) + r * 4;
        uint4 q0 = xr[0], q1 = xr[1], q2 = xr[2], q3 = xr[3];
        uint32_t xv[16] = {q0.x, q0.y, q0.z, q0.w,
                           q1.x, q1.y, q1.z, q1.w,
                           q2.x, q2.y, q2.z, q2.w,
                           q3.x, q3.y, q3.z, q3.w};
        uint32_t a0 = 0, a1 = 0, a2 = 0, a3 = 0;
#pragma unroll
        for (int i = 0; i < 16; ++i) {
            a0 ^= xv[i] & g[0][i];
            a1 ^= xv[i] & g[1][i];
            a2 ^= xv[i] & g[2][i];
            a3 ^= xv[i] & g[3][i];
        }
        float4 o;
        o.x = (float)(__popc(a0) & 1);
        o.y = (float)(__popc(a1) & 1);
        o.z = (float)(__popc(a2) & 1);
        o.w = (float)(__popc(a3) & 1);
        reinterpret_cast<float4*>(out + (size_t)(b0 + r) * 1024)[tid] = o;
    }
}

// ---------------------------------------------------------------------------
extern "C" void kernel_launch(void* const* d_in, const int* in_sizes, int n_in,
                              void* d_out, int out_size, void* d_ws, size_t ws_size,
                              hipStream_t stream) {
    const float* x = (const float*)d_in[0];   // [B][512]
    const float* G = (const float*)d_in[1];   // [N][512]
    float* out = (float*)d_out;

    const int B = 131072;
    // Workspace: gp (64 KiB) | xp (8 MiB)
    unsigned long long* gp64 = (unsigned long long*)d_ws;
    unsigned long long* xp64 = (unsigned long long*)((char*)d_ws + 65536);

    // Pack G: 2048 chunks, 4 waves/block -> 512 blocks, one chunk per wave.
    pack256_kernel<<<512, 256, 0, stream>>>(G, gp64, 2048);
    // Pack x: 262144 chunks, grid-stride (32 chunks per wave).
    pack256_kernel<<<2048, 256, 0, stream>>>(x, xp64, 262144);
    // Encode: one block per 64 rows.
    gf2_encode_kernel<<<B / 64, 256, 0, stream>>>(
        (const uint32_t*)xp64, (const uint32_t*)gp64, out);
}

// Round 7
// 281.884 us; speedup vs baseline: 6.8888x; 6.8888x over previous
//
#include <hip/hip_runtime.h>
#include <cstdint>

// GF(2) encoder: out[b][n] = parity( x_row[b] & g_row[n] ), bit-packed.
// B=131072, K=512, N=1024.
//
// Packing scheme (component-major, identical for x and G so parity is
// invariant): a 256-float chunk handled by one wave becomes 4 u64 words,
// word j bit i = (chunk[i*4 + j] != 0). Row of K=512 floats = 2 chunks =
// 8 u64 = 16 u32, contiguous.
//
// VGPR-cap history (the recurring bug):
//   R2: __launch_bounds__(256,3) -> cap 84 < ~90 live -> spill, 4 ms
//   R6: no attribute -> default cap 64 < ~100 live -> spill, 1.9 ms
//   R7: __launch_bounds__(256,2) -> cap 256 >> ~110 live -> no spill.
// Layout: 256 thr x 4 cols (g[4][16]=64 VGPR), halves the broadcast
// ds_read stream vs 2-col (R4: 185 us encode = LDS 82 + VALU 60 + store 82).

// ---------------------------------------------------------------------------
// Pack: one wave per 256-float chunk, grid-strided. 16B/lane coalesced reads.
__global__ void pack256_kernel(const float* __restrict__ in,
                               unsigned long long* __restrict__ out,
                               int nChunks) {
    const int nWaves = (gridDim.x * blockDim.x) >> 6;
    const int lane = threadIdx.x & 63;
    for (int chunk = (blockIdx.x * blockDim.x + threadIdx.x) >> 6;
         chunk < nChunks; chunk += nWaves) {
        const float4 v =
            reinterpret_cast<const float4*>(in + (size_t)chunk * 256)[lane];
        unsigned long long m0 = __ballot(v.x != 0.0f);
        unsigned long long m1 = __ballot(v.y != 0.0f);
        unsigned long long m2 = __ballot(v.z != 0.0f);
        unsigned long long m3 = __ballot(v.w != 0.0f);
        if (lane == 0) {
            unsigned long long* o = out + (size_t)chunk * 4;
            o[0] = m0; o[1] = m1; o[2] = m2; o[3] = m3;
        }
    }
}

// ---------------------------------------------------------------------------
// Encode: block of 256 threads, each thread owns 4 columns (block = all
// 1024). 64 rows staged in LDS (4 KiB, one uint4 per thread), read back as
// broadcast ds_read_b128 (conflict-free).
__global__ __launch_bounds__(256, 2) void gf2_encode_kernel(
    const uint32_t* __restrict__ xp,  // [B][16] packed x rows
    const uint32_t* __restrict__ gp,  // [N][16] packed G rows
    float* __restrict__ out) {        // [B][1024]
    __shared__ uint32_t xl[64 * 16];  // 64 rows x 16 u32 = 4 KiB

    const int tid = threadIdx.x;
    const long long b0 = (long long)blockIdx.x * 64;

    // This thread's 4 G rows (64 VGPRs). G packed = 64 KiB -> L2-resident.
    uint32_t g[4][16];
#pragma unroll
    for (int j = 0; j < 4; ++j) {
        const uint4* gr =
            reinterpret_cast<const uint4*>(gp + (size_t)(tid * 4 + j) * 16);
        uint4 a = gr[0], b = gr[1], c = gr[2], d = gr[3];
        g[j][0] = a.x;  g[j][1] = a.y;  g[j][2] = a.z;  g[j][3] = a.w;
        g[j][4] = b.x;  g[j][5] = b.y;  g[j][6] = b.z;  g[j][7] = b.w;
        g[j][8] = c.x;  g[j][9] = c.y;  g[j][10] = c.z; g[j][11] = c.w;
        g[j][12] = d.x; g[j][13] = d.y; g[j][14] = d.z; g[j][15] = d.w;
    }

    // Stage 64 packed rows: 256 threads x 16B = 4 KiB, one coalesced shot.
    reinterpret_cast<uint4*>(xl)[tid] =
        reinterpret_cast<const uint4*>(xp + b0 * 16)[tid];
    __syncthreads();

    // 64 rows; x row via broadcast ds_read_b128 (conflict-free).
#pragma unroll 2
    for (int r = 0; r < 64; ++r) {
        const uint4* xr = reinterpret_cast<const uint4*>(xl) + r * 4;
        uint4 q0 = xr[0], q1 = xr[1], q2 = xr[2], q3 = xr[3];
        uint32_t xv[16] = {q0.x, q0.y, q0.z, q0.w,
                           q1.x, q1.y, q1.z, q1.w,
                           q2.x, q2.y, q2.z, q2.w,
                           q3.x, q3.y, q3.z, q3.w};
        uint32_t a0 = 0, a1 = 0, a2 = 0, a3 = 0;
#pragma unroll
        for (int i = 0; i < 16; ++i) {
            a0 ^= xv[i] & g[0][i];
            a1 ^= xv[i] & g[1][i];
            a2 ^= xv[i] & g[2][i];
            a3 ^= xv[i] & g[3][i];
        }
        float4 o;
        o.x = (float)(__popc(a0) & 1);
        o.y = (float)(__popc(a1) & 1);
        o.z = (float)(__popc(a2) & 1);
        o.w = (float)(__popc(a3) & 1);
        reinterpret_cast<float4*>(out + (size_t)(b0 + r) * 1024)[tid] = o;
    }
}

// ---------------------------------------------------------------------------
extern "C" void kernel_launch(void* const* d_in, const int* in_sizes, int n_in,
                              void* d_out, int out_size, void* d_ws, size_t ws_size,
                              hipStream_t stream) {
    const float* x = (const float*)d_in[0];   // [B][512]
    const float* G = (const float*)d_in[1];   // [N][512]
    float* out = (float*)d_out;

    const int B = 131072;
    // Workspace: gp (64 KiB) | xp (8 MiB)
    unsigned long long* gp64 = (unsigned long long*)d_ws;
    unsigned long long* xp64 = (unsigned long long*)((char*)d_ws + 65536);

    // Pack G: 2048 chunks, 4 waves/block -> 512 blocks, one chunk per wave.
    pack256_kernel<<<512, 256, 0, stream>>>(G, gp64, 2048);
    // Pack x: 262144 chunks, grid-stride (32 chunks per wave).
    pack256_kernel<<<2048, 256, 0, stream>>>(x, xp64, 262144);
    // Encode: one block per 64 rows.
    gf2_encode_kernel<<<B / 64, 256, 0, stream>>>(
        (const uint32_t*)xp64, (const uint32_t*)gp64, out);
}

// Round 8
// 215.452 us; speedup vs baseline: 9.0129x; 1.3083x over previous
//
#include <hip/hip_runtime.h>
#include <cstdint>

// GF(2) encoder: out[b][n] = parity( x_row[b] & g_row[n] ), bit-packed.
// B=131072, K=512, N=1024.
//
// Packing scheme (component-major, identical for x and G so parity is
// invariant): a 256-float chunk handled by one wave becomes 4 u64 words,
// word j bit i = (chunk[i*4 + j] != 0). Row = 2 chunks = 16 u32.
//
// History:
//  R2/R6: 4-col layouts spilled (VGPR cap < live) -> HBM thrash.
//  R7: 4-col + LB(256,2) -> no spill but 2 waves/SIMD -> latency-bound.
//  R4 (best, 185us encode): 2-col, 512thr, ~60 live, 8 waves/SIMD; limited
//    by 3 poorly-overlapping streams {LDS-broadcast ~82, VALU ~64, store ~79}.
//  R5: SMEM x-row with per-row glued waitcnt -> serialized, regression.
//  R8 (this): 2-col + x-row in SGPRs via BATCHED s_load_dwordx16 (4 rows
//    per wait, loads hoistable/prefetchable, consumers tied to the waitcnt
//    via "+s" SSA deps). No LDS at all. LB(512,8), live ~46 VGPR.

typedef uint32_t u32x16 __attribute__((ext_vector_type(16)));

// ---------------------------------------------------------------------------
// Pack: one wave per 256-float chunk, grid-strided. 16B/lane coalesced reads.
__global__ void pack256_kernel(const float* __restrict__ in,
                               unsigned long long* __restrict__ out,
                               int nChunks) {
    const int nWaves = (gridDim.x * blockDim.x) >> 6;
    const int lane = threadIdx.x & 63;
    for (int chunk = (blockIdx.x * blockDim.x + threadIdx.x) >> 6;
         chunk < nChunks; chunk += nWaves) {
        const float4 v =
            reinterpret_cast<const float4*>(in + (size_t)chunk * 256)[lane];
        unsigned long long m0 = __ballot(v.x != 0.0f);
        unsigned long long m1 = __ballot(v.y != 0.0f);
        unsigned long long m2 = __ballot(v.z != 0.0f);
        unsigned long long m3 = __ballot(v.w != 0.0f);
        if (lane == 0) {
            unsigned long long* o = out + (size_t)chunk * 4;
            o[0] = m0; o[1] = m1; o[2] = m2; o[3] = m3;
        }
    }
}

// ---------------------------------------------------------------------------
// Encode: 512 threads, 2 cols/thread. Per 4-row batch, the wave-uniform
// packed x rows are loaded into 64 SGPRs (4x s_load_dwordx16); one waitcnt
// per batch, consumers depend on its "+s" outputs. AND = v_and v,s,v.
__global__ __launch_bounds__(512, 8) void gf2_encode_kernel(
    const uint32_t* __restrict__ xp,  // [B][16] packed x rows
    const uint32_t* __restrict__ gp,  // [N][16] packed G rows
    float* __restrict__ out) {        // [B][1024]
    const int tid = threadIdx.x;
    const long long b0 = (long long)blockIdx.x * 64;

    // This thread's 2 G rows (32 VGPRs). G packed = 64 KiB -> L2-resident.
    uint32_t g[2][16];
#pragma unroll
    for (int j = 0; j < 2; ++j) {
        const uint4* gr =
            reinterpret_cast<const uint4*>(gp + (size_t)(tid * 2 + j) * 16);
        uint4 a = gr[0], b = gr[1], c = gr[2], d = gr[3];
        g[j][0] = a.x;  g[j][1] = a.y;  g[j][2] = a.z;  g[j][3] = a.w;
        g[j][4] = b.x;  g[j][5] = b.y;  g[j][6] = b.z;  g[j][7] = b.w;
        g[j][8] = c.x;  g[j][9] = c.y;  g[j][10] = c.z; g[j][11] = c.w;
        g[j][12] = d.x; g[j][13] = d.y; g[j][14] = d.z; g[j][15] = d.w;
    }

    const uint32_t* xrow = xp + b0 * 16;
    float* orow = out + b0 * 1024;

    for (int batch = 0; batch < 16; ++batch) {
        // Issue 4 wave-uniform row loads (256 B). Non-volatile: the compiler
        // may hoist/schedule them early (prefetch); DCE impossible (outputs
        // consumed below).
        u32x16 x0, x1, x2, x3;
        asm("s_load_dwordx16 %0, %1, 0x0"  : "=s"(x0) : "s"(xrow));
        asm("s_load_dwordx16 %0, %1, 0x40" : "=s"(x1) : "s"(xrow));
        asm("s_load_dwordx16 %0, %1, 0x80" : "=s"(x2) : "s"(xrow));
        asm("s_load_dwordx16 %0, %1, 0xc0" : "=s"(x3) : "s"(xrow));
        // One wait per batch; "+s" ties consumers to post-wait values (SSA
        // dep -> no rule-#18 hoisting hazard, no sched_barrier needed).
        asm volatile("s_waitcnt lgkmcnt(0)"
                     : "+s"(x0), "+s"(x1), "+s"(x2), "+s"(x3));

        const u32x16* xb[4] = {&x0, &x1, &x2, &x3};
#pragma unroll
        for (int r = 0; r < 4; ++r) {
            const u32x16 xv = *xb[r];
            uint32_t a0 = 0, a1 = 0;
#pragma unroll
            for (int i = 0; i < 16; ++i) {
                a0 ^= xv[i] & g[0][i];
                a1 ^= xv[i] & g[1][i];
            }
            float2 o;
            o.x = (float)(__popc(a0) & 1);
            o.y = (float)(__popc(a1) & 1);
            reinterpret_cast<float2*>(orow)[tid] = o;
            orow += 1024;
        }
        xrow += 64;
    }
}

// ---------------------------------------------------------------------------
extern "C" void kernel_launch(void* const* d_in, const int* in_sizes, int n_in,
                              void* d_out, int out_size, void* d_ws, size_t ws_size,
                              hipStream_t stream) {
    const float* x = (const float*)d_in[0];   // [B][512]
    const float* G = (const float*)d_in[1];   // [N][512]
    float* out = (float*)d_out;

    const int B = 131072;
    // Workspace: gp (64 KiB) | xp (8 MiB)
    unsigned long long* gp64 = (unsigned long long*)d_ws;
    unsigned long long* xp64 = (unsigned long long*)((char*)d_ws + 65536);

    // Pack G: 2048 chunks, 4 waves/block -> 512 blocks, one chunk per wave.
    pack256_kernel<<<512, 256, 0, stream>>>(G, gp64, 2048);
    // Pack x: 262144 chunks, grid-stride (32 chunks per wave).
    pack256_kernel<<<2048, 256, 0, stream>>>(x, xp64, 262144);
    // Encode: one block per 64 rows.
    gf2_encode_kernel<<<B / 64, 512, 0, stream>>>(
        (const uint32_t*)xp64, (const uint32_t*)gp64, out);
}

// Round 9
// 202.902 us; speedup vs baseline: 9.5703x; 1.0619x over previous
//
#include <hip/hip_runtime.h>
#include <cstdint>

// GF(2) encoder: out[b][n] = parity( x_row[b] & g_row[n] ).
// B=131072, K=512, N=1024.
//
// R9 structure: ONE fused kernel. Each wave packs the x rows it needs via
// __ballot (result lands directly in SGPRs -- the packed-x intermediate,
// the pack_x kernel, LDS, barriers, and SMEM waits all disappear).
// Component-major bit order identical to pack256 (used for G), so parity
// is preserved: chunk of 256 floats -> 4 u64, word j bit i = elem[i*4+j].
//
// History: R2/R6 spills (cap<live); R7 cap-256 -> 2 waves/EU latency-bound;
// R4/R8 split-kernel best 215us, encode ~167 vs 79us store floor -- killed
// by pack_x serialization + x-delivery dependency chains. R9 removes both.

// ---------------------------------------------------------------------------
// Pack G only: one wave per 256-float chunk. nChunks = N*K/256 = 2048.
__global__ void pack256_kernel(const float* __restrict__ in,
                               unsigned long long* __restrict__ out,
                               int nChunks) {
    const int chunk = blockIdx.x * (blockDim.x >> 6) + (threadIdx.x >> 6);
    const int lane = threadIdx.x & 63;
    if (chunk >= nChunks) return;
    const float4 v =
        reinterpret_cast<const float4*>(in + (size_t)chunk * 256)[lane];
    unsigned long long m0 = __ballot(v.x != 0.0f);
    unsigned long long m1 = __ballot(v.y != 0.0f);
    unsigned long long m2 = __ballot(v.z != 0.0f);
    unsigned long long m3 = __ballot(v.w != 0.0f);
    if (lane == 0) {
        unsigned long long* o = out + (size_t)chunk * 4;
        o[0] = m0; o[1] = m1; o[2] = m2; o[3] = m3;
    }
}

// ---------------------------------------------------------------------------
// Fused encode: 256 threads, 4 cols/thread (block covers N=1024).
// Each wave independently streams the block's 64 x-rows (2 float4/lane/row,
// prefetched one row ahead), ballots them into 16 uniform SGPRs, and
// AND/XOR-folds against G fragments held in VGPRs. float4 stores.
// Live VGPR ~100: g 64 + prefetch 8 + cur 8 + accs 4 + addr/misc.
// LB(256,4) -> cap 128: no spill, 16 waves/CU.
__global__ __launch_bounds__(256, 4) void gf2_fused_kernel(
    const float* __restrict__ x,      // [B][512] 0/1 floats
    const uint32_t* __restrict__ gp,  // [N][16] packed G rows
    float* __restrict__ out) {        // [B][1024]
    const int tid = threadIdx.x;
    const int lane = tid & 63;
    const long long b0 = (long long)blockIdx.x * 64;

    // This thread's 4 G rows (64 VGPRs). G packed = 64 KiB -> L2-resident.
    uint32_t g[4][16];
#pragma unroll
    for (int j = 0; j < 4; ++j) {
        const uint4* gr =
            reinterpret_cast<const uint4*>(gp + (size_t)(tid * 4 + j) * 16);
        uint4 a = gr[0], b = gr[1], c = gr[2], d = gr[3];
        g[j][0] = a.x;  g[j][1] = a.y;  g[j][2] = a.z;  g[j][3] = a.w;
        g[j][4] = b.x;  g[j][5] = b.y;  g[j][6] = b.z;  g[j][7] = b.w;
        g[j][8] = c.x;  g[j][9] = c.y;  g[j][10] = c.z; g[j][11] = c.w;
        g[j][12] = d.x; g[j][13] = d.y; g[j][14] = d.z; g[j][15] = d.w;
    }

    // Wave-private x stream, software-prefetched one row ahead.
    const float* xr = x + b0 * 512 + lane * 4;
    float4 p0 = *reinterpret_cast<const float4*>(xr);
    float4 p1 = *reinterpret_cast<const float4*>(xr + 256);

    for (int r = 0; r < 64; ++r) {
        const float4 c0 = p0, c1 = p1;
        if (r < 63) {
            xr += 512;
            p0 = *reinterpret_cast<const float4*>(xr);
            p1 = *reinterpret_cast<const float4*>(xr + 256);
        }
        // Ballot-pack this row into 16 wave-uniform u32 (SGPRs).
        unsigned long long m0 = __ballot(c0.x != 0.0f);
        unsigned long long m1 = __ballot(c0.y != 0.0f);
        unsigned long long m2 = __ballot(c0.z != 0.0f);
        unsigned long long m3 = __ballot(c0.w != 0.0f);
        unsigned long long m4 = __ballot(c1.x != 0.0f);
        unsigned long long m5 = __ballot(c1.y != 0.0f);
        unsigned long long m6 = __ballot(c1.z != 0.0f);
        unsigned long long m7 = __ballot(c1.w != 0.0f);
        const uint32_t xv[16] = {
            (uint32_t)m0, (uint32_t)(m0 >> 32),
            (uint32_t)m1, (uint32_t)(m1 >> 32),
            (uint32_t)m2, (uint32_t)(m2 >> 32),
            (uint32_t)m3, (uint32_t)(m3 >> 32),
            (uint32_t)m4, (uint32_t)(m4 >> 32),
            (uint32_t)m5, (uint32_t)(m5 >> 32),
            (uint32_t)m6, (uint32_t)(m6 >> 32),
            (uint32_t)m7, (uint32_t)(m7 >> 32)};

        uint32_t a0 = 0, a1 = 0, a2 = 0, a3 = 0;
#pragma unroll
        for (int i = 0; i < 16; ++i) {
            a0 ^= xv[i] & g[0][i];
            a1 ^= xv[i] & g[1][i];
            a2 ^= xv[i] & g[2][i];
            a3 ^= xv[i] & g[3][i];
        }
        float4 o;
        o.x = (float)(__popc(a0) & 1);
        o.y = (float)(__popc(a1) & 1);
        o.z = (float)(__popc(a2) & 1);
        o.w = (float)(__popc(a3) & 1);
        reinterpret_cast<float4*>(out + (size_t)(b0 + r) * 1024)[tid] = o;
    }
}

// ---------------------------------------------------------------------------
extern "C" void kernel_launch(void* const* d_in, const int* in_sizes, int n_in,
                              void* d_out, int out_size, void* d_ws, size_t ws_size,
                              hipStream_t stream) {
    const float* x = (const float*)d_in[0];   // [B][512]
    const float* G = (const float*)d_in[1];   // [N][512]
    float* out = (float*)d_out;

    const int B = 131072;
    // Workspace: gp (64 KiB)
    unsigned long long* gp64 = (unsigned long long*)d_ws;

    // Pack G: 2048 chunks, 4 waves/block -> 512 blocks.
    pack256_kernel<<<512, 256, 0, stream>>>(G, gp64, 2048);
    // Fused ballot-pack + encode: one block per 64 rows.
    gf2_fused_kernel<<<B / 64, 256, 0, stream>>>(
        x, (const uint32_t*)gp64, out);
}